// Round 20
// baseline (58.882 us; speedup 1.0000x reference)
//
#include <hip/hip_runtime.h>

// ConvDatapath: bit-serial crossbar conv with per-chunk ADC quantization.
// k_q v3: ONE ROW PER WAVE (6400 waves = 6.25/SIMD; was 1600 = 1.56/SIMD).
//         No LDS, no barriers, no repack: quantized bytes go to ROW-MAJOR
//         global rows (64-contiguous byte stores) + zeroed 64B row pad.
// k_d   : R11 structure verbatim; MFMA fragments assembled in-register from
//         row-major rows via 4x dword loads (116 % 4 == 0) with ks1/g3
//         masking (k 116..127 pad -> 0). Integer path bit-exact vs ref.
// Nx = 6272, Ny = 128, K = 576 (5 chunks of 116, padded to 128 in-reg).

#define NXROW 6272
#define RMS   640     // row-major row stride (576 data + 64 zero pad)

typedef int i32x4 __attribute__((ext_vector_type(4)));

__device__ __forceinline__ i32x4 slice2b(i32x4 v, int sh) {
    i32x4 r;
    r[0] = (int)(((unsigned)v[0] >> sh) & 0x03030303u);
    r[1] = (int)(((unsigned)v[1] >> sh) & 0x03030303u);
    r[2] = (int)(((unsigned)v[2] >> sh) & 0x03030303u);
    r[3] = (int)(((unsigned)v[3] >> sh) & 0x03030303u);
    return r;
}

// ---------------- kernel 1: quantization, one row per wave ----------------
// wave W < 6272: im2col x-row W. wave W >= 6272: w-row (W-6272).
// lane holds k = r*64+lane, r = 0..8 (576 = 9*64 exactly).
__global__ __launch_bounds__(256) void k_q(
    const float* __restrict__ x, const float* __restrict__ w,
    unsigned char* __restrict__ Xq, unsigned char* __restrict__ Wq,
    float* __restrict__ xsc, float* __restrict__ xof, float* __restrict__ xsm,
    float* __restrict__ wsc, float* __restrict__ wof, float* __restrict__ wsm)
{
    int tid = threadIdx.x, wv = tid >> 6, lane = tid & 63;
    int W = blockIdx.x * 4 + wv;          // 0..6399, wave-uniform

    float v[9];
    unsigned char* rowp;
    float *sc, *of, *sm;
    int sidx;

    if (W < NXROW) {
        int b = W >= 3136 ? 1 : 0;
        int pos = W - b * 3136;
        int hg = pos / 56, wg = pos - hg * 56;
        const float* xb = x + (size_t)(b * 64) * 3136;
#pragma unroll
        for (int r = 0; r < 9; r++) {
            int k = r * 64 + lane;
            int cin = k / 9;              // magic-mul
            int off = k - cin * 9;        // [cin][kh][kw] ordering (ref im2col)
            int kh = off / 3;
            int kw = off - kh * 3;
            int hr = hg - 1 + kh, wc = wg - 1 + kw;
            bool ok = ((unsigned)hr < 56u) && ((unsigned)wc < 56u);
            v[r] = ok ? xb[cin * 3136 + hr * 56 + wc] : 0.f;
        }
        rowp = Xq + (size_t)W * RMS;
        sc = xsc; of = xof; sm = xsm; sidx = W;
    } else {
        int row = W - NXROW;              // 0..127
        const float* wr = w + (size_t)row * 576;
#pragma unroll
        for (int r = 0; r < 9; r++) v[r] = wr[r * 64 + lane];
        rowp = Wq + (size_t)row * RMS;
        sc = wsc; of = wof; sm = wsm; sidx = row;
    }

    // stats: exact min/max (order-free); sum order enters only the tiny
    // additive correction terms (~1e-5 absolute) — threshold-safe.
    float mn = v[0], mx = v[0], s = 0.f;
#pragma unroll
    for (int r = 0; r < 9; r++) { mn = fminf(mn, v[r]); mx = fmaxf(mx, v[r]); s += v[r]; }
#pragma unroll
    for (int off = 1; off < 64; off <<= 1) {
        mn = fminf(mn, __shfl_xor(mn, off));
        mx = fmaxf(mx, __shfl_xor(mx, off));
        s += __shfl_xor(s, off);
    }
    float step = (mx - mn) / 255.0f;      // IEEE — bit-exact vs reference
    if (lane == 0) { sc[sidx] = step; of[sidx] = mn; sm[sidx] = s; }

#pragma unroll
    for (int r = 0; r < 9; r++) {
        int q = (int)rintf((v[r] - mn) / step);   // IEEE div — bit-exact
        q = q < 0 ? 0 : (q > 255 ? 255 : q);
        rowp[r * 64 + lane] = (unsigned char)q;   // 64-contiguous per instr
    }
    rowp[576 + lane] = 0;                 // zero row pad (chunk-4 k 576..579)
}

// ---------------- kernel 2: crossbar MFMA + ADC + dequant ----------------
// fragment dwords from row-major row rp: k = ch*116 + ks*64 + g*16 + 4m.
__device__ __forceinline__ i32x4 ldfrag0(const unsigned char* rp, int ch, int g) {
    const int* p = (const int*)(rp + ch * 116 + g * 16);
    i32x4 r = {p[0], p[1], p[2], p[3]};
    return r;
}
__device__ __forceinline__ i32x4 ldfrag1(const unsigned char* rp, int ch, int g) {
    const int* p = (const int*)(rp + ch * 116 + 64 + g * 16);
    bool gm = (g == 3);                   // k_local 116..127 -> MFMA pad = 0
    i32x4 r = {p[0], gm ? 0 : p[1], gm ? 0 : p[2], gm ? 0 : p[3]};
    return r;
}

// one chunk, accumulating into 4 per-ws accumulators (4 indep chains)
__device__ __forceinline__ void chunk_ws(const unsigned char* xr, const unsigned char* wr,
                                         int ch, int g, i32x4 (&acc4)[4])
{
    const i32x4 zero = {0, 0, 0, 0};
    i32x4 x0 = ldfrag0(xr, ch, g), x1 = ldfrag1(xr, ch, g);
    i32x4 w0 = ldfrag0(wr, ch, g), w1 = ldfrag1(wr, ch, g);
    i32x4 ws0[4], ws1[4];
#pragma unroll
    for (int ws = 0; ws < 4; ws++) {
        ws0[ws] = slice2b(w0, 6 - 2 * ws);
        ws1[ws] = slice2b(w1, 6 - 2 * ws);
    }
#pragma unroll
    for (int is = 0; is < 4; is++) {
        int ish = 6 - 2 * is;
        i32x4 a0 = slice2b(x0, ish), a1 = slice2b(x1, ish);
#pragma unroll
        for (int ws = 0; ws < 4; ws++) {
            i32x4 d = __builtin_amdgcn_mfma_i32_16x16x64_i8(ws0[ws], a0, zero, 0, 0, 0);
            d = __builtin_amdgcn_mfma_i32_16x16x64_i8(ws1[ws], a1, d, 0, 0, 0);
            int sh = ish + 6 - 2 * ws;
#pragma unroll
            for (int r = 0; r < 4; r++) {
                int z = d[r];
                z = z > 1024 ? 1024 : z;                 // ADC clip (z >= 0)
                int t = (z >> 2) & 1;
                int r4 = (z + 1 + t) & ~3;               // round-half-even, mult of 4
                acc4[ws][r] += r4 << sh;                 // 2^(ish+wsh)
            }
        }
    }
}

__global__ __launch_bounds__(256) void k_d(
    const unsigned char* __restrict__ Xq, const unsigned char* __restrict__ Wq,
    const float* __restrict__ xscg, const float* __restrict__ xofg,
    const float* __restrict__ xsmg,
    const float* __restrict__ wscg, const float* __restrict__ wofg,
    const float* __restrict__ wsmg, float* __restrict__ out)
{
    __shared__ __align__(16) int pacc[2][64][4];

    int tid = threadIdx.x, wv = tid >> 6, lane = tid & 63;
    int g = lane >> 4, i16 = lane & 15;
    int blk = blockIdx.x;                 // 0..1567
    int ct = blk & 7, rp = blk >> 3;      // rp 0..195
    int tl = wv & 1, khalf = wv >> 1;
    int rtile = rp * 2 + tl;              // 0..391
    const unsigned char* xr = Xq + (size_t)(rtile * 16 + i16) * RMS;
    const unsigned char* wr = Wq + (size_t)(ct * 16 + i16) * RMS;

    i32x4 acc4[4] = {{0,0,0,0},{0,0,0,0},{0,0,0,0},{0,0,0,0}};
    if (khalf == 0) {
        chunk_ws(xr, wr, 0, g, acc4);
        chunk_ws(xr, wr, 1, g, acc4);
        chunk_ws(xr, wr, 2, g, acc4);
    } else {
        chunk_ws(xr, wr, 3, g, acc4);
        chunk_ws(xr, wr, 4, g, acc4);
    }
    i32x4 acc;
#pragma unroll
    for (int r = 0; r < 4; r++)
        acc[r] = (acc4[0][r] + acc4[1][r]) + (acc4[2][r] + acc4[3][r]);  // exact

    if (khalf == 0) *(i32x4*)&pacc[tl][lane][0] = acc;
    __syncthreads();

    if (khalf == 1) {
        i32x4 p = *(const i32x4*)&pacc[tl][lane][0];
#pragma unroll
        for (int r = 0; r < 4; r++) acc[r] += p[r];      // chunk-sum, exact

        // epilogue: D[row = w-row (g*4+r), col = x-row (i16)]; 64B coalesced
        int b = rtile >= 196 ? 1 : 0;
        int xrow = rtile * 16 + i16;
        float xs_ = xscg[xrow], xo = xofg[xrow], xsv = xsmg[xrow];
        int hw = (rtile - 196 * b) * 16 + i16;
#pragma unroll
        for (int r = 0; r < 4; r++) {
            int wrow = ct * 16 + g * 4 + r;
            float tt = ((float)acc[r] * xs_) * wscg[wrow];
            float res = ((tt + xo * wsmg[wrow]) + wofg[wrow] * xsv)
                      - (xo * wofg[wrow]) * 576.0f;
            out[(size_t)(b * 128 + wrow) * 3136 + hw] = res;
        }
    }
}

extern "C" void kernel_launch(void* const* d_in, const int* in_sizes, int n_in,
                              void* d_out, int out_size, void* d_ws, size_t ws_size,
                              hipStream_t stream) {
    const float* x = (const float*)d_in[0];   // [2][64][56][56]
    const float* w = (const float*)d_in[1];   // [128][64][3][3]
    float* out = (float*)d_out;               // [2][128][56][56]

    unsigned char* Xq = (unsigned char*)d_ws;          // 6272*640 = 4,014,080 B
    unsigned char* Wq = Xq + (size_t)NXROW * RMS;      // 128*640   = 81,920 B
    float* xsc = (float*)(Wq + 128 * RMS);
    float* xof = xsc + NXROW;
    float* xsm = xof + NXROW;
    float* wsc = xsm + NXROW;
    float* wof = wsc + 128;
    float* wsm = wof + 128;

    hipLaunchKernelGGL(k_q, dim3(1600), dim3(256), 0, stream,
                       x, w, Xq, Wq, xsc, xof, xsm, wsc, wof, wsm);
    hipLaunchKernelGGL(k_d, dim3(1568), dim3(256), 0, stream,
                       Xq, Wq, xsc, xof, xsm, wsc, wof, wsm, out);
}

// Round 21
// 33.900 us; speedup vs baseline: 1.7369x; 1.7369x over previous
//
#include <hip/hip_runtime.h>

// ConvDatapath: bit-serial crossbar conv with per-chunk ADC quantization.
// R20 A/B result: fragment-layout k_d = 18.6us vs row-major k_d = 46.4us;
// one-row-per-wave k_q = 12.4us vs staged k_q = 18.5us. This round combines
// the winners:
// k_q v4: one row per wave (6400 waves). Quant bytes -> private 656B LDS row
//         (R11 stride, conflict-free) -> barrier -> per-lane 16B segments
//         stored DIRECTLY in fragment layout to global (copy_out formula).
// k_d   : R11 verbatim (fragment-layout 16B coalesced loads, khalf split).
// Integer path bit-exact vs reference. Nx=6272, Ny=128, K=576 (5x116->128).

#define NXROW 6272
#define KDIM  576
#define NPB   116
#define SSTR  656    // LDS row stride: 41*16, b128-aligned, 164 dw % 32 = 4

typedef int i32x4 __attribute__((ext_vector_type(4)));
typedef float f32x4 __attribute__((ext_vector_type(4)));

__device__ __forceinline__ i32x4 slice2b(i32x4 v, int sh) {
    i32x4 r;
    r[0] = (int)(((unsigned)v[0] >> sh) & 0x03030303u);
    r[1] = (int)(((unsigned)v[1] >> sh) & 0x03030303u);
    r[2] = (int)(((unsigned)v[2] >> sh) & 0x03030303u);
    r[3] = (int)(((unsigned)v[3] >> sh) & 0x03030303u);
    return r;
}

// ---------------- kernel 1: quantization, one row per wave ----------------
// wave W < 6272: im2col x-row W. wave W >= 6272: w-row (W-6272).
// lane holds k = r*64+lane, r = 0..8 (576 = 9*64).
__global__ __launch_bounds__(256) void k_q(
    const float* __restrict__ x, const float* __restrict__ w,
    unsigned char* __restrict__ Xq, unsigned char* __restrict__ Wq,
    float* __restrict__ xsc, float* __restrict__ xof, float* __restrict__ xsm,
    float* __restrict__ wsc, float* __restrict__ wof, float* __restrict__ wsm)
{
    __shared__ __align__(16) unsigned char scr[4][SSTR];  // per-wave row

    int tid = threadIdx.x, wv = tid >> 6, lane = tid & 63;
    int W = blockIdx.x * 4 + wv;          // 0..6399, wave-uniform
    unsigned char* myrow = scr[wv];

    // zero the K-pad dwords of this wave's row (cols ch*128+116..127, 624..639)
    if (lane < 16) {
        int col = lane < 12 ? (lane / 3) * 128 + 116 + (lane % 3) * 4
                            : 624 + (lane - 12) * 4;
        *(unsigned int*)(myrow + col) = 0u;
    }

    float v[9];
    unsigned char* dstbase;
    int rl;
    float *sc, *of, *sm;
    int sidx;

    if (W < NXROW) {
        int b = W >= 3136 ? 1 : 0;
        int pos = W - b * 3136;
        int hg = pos / 56, wg = pos - hg * 56;
        const float* xb = x + (size_t)(b * 64) * 3136;
#pragma unroll
        for (int r = 0; r < 9; r++) {
            int k = r * 64 + lane;
            int cin = k / 9;              // magic-mul
            int off = k - cin * 9;        // [cin][kh][kw] (ref im2col order)
            int kh = off / 3;
            int kw = off - kh * 3;
            int hr = hg - 1 + kh, wc = wg - 1 + kw;
            bool ok = ((unsigned)hr < 56u) && ((unsigned)wc < 56u);
            v[r] = ok ? xb[cin * 3136 + hr * 56 + wc] : 0.f;
        }
        dstbase = Xq + (size_t)(W >> 4) * 10240;  rl = W & 15;
        sc = xsc; of = xof; sm = xsm; sidx = W;
    } else {
        int row = W - NXROW;              // 0..127
        const float* wr = w + (size_t)row * KDIM;
#pragma unroll
        for (int r = 0; r < 9; r++) v[r] = wr[r * 64 + lane];
        dstbase = Wq + (size_t)(row >> 4) * 10240;  rl = row & 15;
        sc = wsc; of = wof; sm = wsm; sidx = row;
    }

    // stats: exact min/max; sum via butterfly (enters only the tiny additive
    // correction terms — R20 passed at absmax 0.75 with this exact code).
    float mn = v[0], mx = v[0], s = 0.f;
#pragma unroll
    for (int r = 0; r < 9; r++) { mn = fminf(mn, v[r]); mx = fmaxf(mx, v[r]); s += v[r]; }
#pragma unroll
    for (int off2 = 1; off2 < 64; off2 <<= 1) {
        mn = fminf(mn, __shfl_xor(mn, off2));
        mx = fmaxf(mx, __shfl_xor(mx, off2));
        s += __shfl_xor(s, off2);
    }
    float step = (mx - mn) / 255.0f;      // IEEE — bit-exact vs reference
    if (lane == 0) { sc[sidx] = step; of[sidx] = mn; sm[sidx] = s; }

    // quantize into this wave's LDS row: col = k + 12*(k/116) = ch*128 + k%116
#pragma unroll
    for (int r = 0; r < 9; r++) {
        int q = (int)rintf((v[r] - mn) / step);   // IEEE div — bit-exact
        q = q < 0 ? 0 : (q > 255 ? 255 : q);
        int k = r * 64 + lane;
        int ch = k / NPB;
        myrow[k + 12 * ch] = (unsigned char)q;
    }
    __syncthreads();   // uniform: orders LDS byte-writes before segment reads

    // scatter this row into fragment layout: seg u (16B) at col u*16 goes to
    // tile 16B-run dst16 = (u>>3)*128 + ((u>>2)&1)*64 + (u&3)*16 + rl.
    if (lane < 40) {
        int u = lane;
        i32x4 seg = *(const i32x4*)(myrow + u * 16);
        int dst16 = (u >> 3) * 128 + ((u >> 2) & 1) * 64 + (u & 3) * 16 + rl;
        *(i32x4*)(dstbase + (size_t)dst16 * 16) = seg;
    }
}

// ---------------- kernel 2: crossbar MFMA + ADC + dequant (R11 verbatim) ----
// one chunk, accumulating into 4 per-ws accumulators (4 indep chains)
__device__ __forceinline__ void chunk_ws(const unsigned char* xt, const unsigned char* wt,
                                         int ch, int lane, i32x4 (&acc4)[4])
{
    const i32x4 zero = {0, 0, 0, 0};
    i32x4 x0 = *(const i32x4*)(xt + ch * 2048 + lane * 16);
    i32x4 x1 = *(const i32x4*)(xt + ch * 2048 + 1024 + lane * 16);
    i32x4 w0 = *(const i32x4*)(wt + ch * 2048 + lane * 16);
    i32x4 w1 = *(const i32x4*)(wt + ch * 2048 + 1024 + lane * 16);
    i32x4 ws0[4], ws1[4];
#pragma unroll
    for (int ws = 0; ws < 4; ws++) {
        ws0[ws] = slice2b(w0, 6 - 2 * ws);
        ws1[ws] = slice2b(w1, 6 - 2 * ws);
    }
#pragma unroll
    for (int is = 0; is < 4; is++) {
        int ish = 6 - 2 * is;
        i32x4 a0 = slice2b(x0, ish), a1 = slice2b(x1, ish);
#pragma unroll
        for (int ws = 0; ws < 4; ws++) {
            i32x4 d = __builtin_amdgcn_mfma_i32_16x16x64_i8(ws0[ws], a0, zero, 0, 0, 0);
            d = __builtin_amdgcn_mfma_i32_16x16x64_i8(ws1[ws], a1, d, 0, 0, 0);
            int sh = ish + 6 - 2 * ws;
#pragma unroll
            for (int r = 0; r < 4; r++) {
                int z = d[r];
                z = z > 1024 ? 1024 : z;                 // ADC clip (z >= 0)
                int t = (z >> 2) & 1;
                int r4 = (z + 1 + t) & ~3;               // round-half-even, mult of 4
                acc4[ws][r] += r4 << sh;                 // 2^(ish+wsh)
            }
        }
    }
}

__global__ __launch_bounds__(256) void k_d(
    const unsigned char* __restrict__ Xq, const unsigned char* __restrict__ Wq,
    const float* __restrict__ xscg, const float* __restrict__ xofg,
    const float* __restrict__ xsmg,
    const float* __restrict__ wscg, const float* __restrict__ wofg,
    const float* __restrict__ wsmg, float* __restrict__ out)
{
    __shared__ __align__(16) int pacc[2][64][4];

    int tid = threadIdx.x, wv = tid >> 6, lane = tid & 63;
    int g = lane >> 4, i16 = lane & 15;
    int blk = blockIdx.x;                 // 0..1567
    int ct = blk & 7, rp = blk >> 3;      // rp 0..195
    int tl = wv & 1, khalf = wv >> 1;
    int rtile = rp * 2 + tl;              // 0..391
    const unsigned char* xt = Xq + (size_t)rtile * 10240;
    const unsigned char* wt = Wq + (size_t)ct * 10240;

    i32x4 acc4[4] = {{0,0,0,0},{0,0,0,0},{0,0,0,0},{0,0,0,0}};
    if (khalf == 0) {
        chunk_ws(xt, wt, 0, lane, acc4);
        chunk_ws(xt, wt, 1, lane, acc4);
        chunk_ws(xt, wt, 2, lane, acc4);
    } else {
        chunk_ws(xt, wt, 3, lane, acc4);
        chunk_ws(xt, wt, 4, lane, acc4);
    }
    i32x4 acc;
#pragma unroll
    for (int r = 0; r < 4; r++)
        acc[r] = (acc4[0][r] + acc4[1][r]) + (acc4[2][r] + acc4[3][r]);  // exact

    if (khalf == 0) *(i32x4*)&pacc[tl][lane][0] = acc;
    __syncthreads();

    if (khalf == 1) {
        i32x4 p = *(const i32x4*)&pacc[tl][lane][0];
#pragma unroll
        for (int r = 0; r < 4; r++) acc[r] += p[r];      // chunk-sum, exact

        // epilogue: D[row = w-row (g*4+r), col = x-row (i16)]; 64B coalesced
        int b = rtile >= 196 ? 1 : 0;
        int xrow = rtile * 16 + i16;
        float xs_ = xscg[xrow], xo = xofg[xrow], xsv = xsmg[xrow];
        int hw = (rtile - 196 * b) * 16 + i16;
#pragma unroll
        for (int r = 0; r < 4; r++) {
            int wrow = ct * 16 + g * 4 + r;
            float tt = ((float)acc[r] * xs_) * wscg[wrow];
            float res = ((tt + xo * wsmg[wrow]) + wofg[wrow] * xsv)
                      - (xo * wofg[wrow]) * 576.0f;
            out[(size_t)(b * 128 + wrow) * 3136 + hw] = res;
        }
    }
}

extern "C" void kernel_launch(void* const* d_in, const int* in_sizes, int n_in,
                              void* d_out, int out_size, void* d_ws, size_t ws_size,
                              hipStream_t stream) {
    const float* x = (const float*)d_in[0];   // [2][64][56][56]
    const float* w = (const float*)d_in[1];   // [128][64][3][3]
    float* out = (float*)d_out;               // [2][128][56][56]

    unsigned char* Xq = (unsigned char*)d_ws;          // 392*10,240 = 4,014,080 B
    unsigned char* Wq = Xq + (size_t)392 * 10240;      // 8*10,240   = 81,920 B
    float* xsc = (float*)(Wq + 8 * 10240);
    float* xof = xsc + NXROW;
    float* xsm = xof + NXROW;
    float* wsc = xsm + NXROW;
    float* wof = wsc + 128;
    float* wsm = wof + 128;

    hipLaunchKernelGGL(k_q, dim3(1600), dim3(256), 0, stream,
                       x, w, Xq, Wq, xsc, xof, xsm, wsc, wof, wsm);
    hipLaunchKernelGGL(k_d, dim3(1568), dim3(256), 0, stream,
                       Xq, Wq, xsc, xof, xsm, wsc, wof, wsm, out);
}